// Round 5
// baseline (324.726 us; speedup 1.0000x reference)
//
#include <hip/hip_runtime.h>
#include <math.h>

#define B_ 64
#define S_ 128
#define E_ 256
#define D_ 128
#define N_ 4096

typedef _Float16 f16;
typedef _Float16 f16x8 __attribute__((ext_vector_type(8)));
typedef float f32x4 __attribute__((ext_vector_type(4)));

__device__ __forceinline__ unsigned pack2(f16 a, f16 b) {
    union { f16 h[2]; unsigned u; } x;
    x.h[0] = a; x.h[1] = b; return x.u;
}

__device__ __forceinline__ f32x4 mfma16(f16x8 a, f16x8 b, f32x4 c) {
    return __builtin_amdgcn_mfma_f32_16x16x32_f16(a, b, c, 0, 0, 0);
}

// LDS-only barrier: does NOT drain vmcnt, so in-flight global loads survive.
__device__ __forceinline__ void bar_lds() {
    asm volatile("s_waitcnt lgkmcnt(0)" ::: "memory");
    __builtin_amdgcn_s_barrier();
    asm volatile("" ::: "memory");
}

// ---------------------------------------------------------------------------
// K1: unchanged from round 4 (MFMA 3-chain; not the measured bottleneck).
// ---------------------------------------------------------------------------
__global__ __launch_bounds__(256) void k1_ep(
    const float* __restrict__ e, const float* __restrict__ W,
    const float* __restrict__ bias,
    unsigned* __restrict__ epA_h, unsigned* __restrict__ epA_l,
    unsigned* __restrict__ epT_h)
{
    __shared__ __align__(16) unsigned char lds[40960];
    f16* ehB = (f16*)lds;                    // [32][64] rows 128B, swz
    f16* elB = (f16*)(lds + 4096);
    f16* WhB = (f16*)(lds + 8192);           // [128][64] rows 128B, swz
    f16* WlB = (f16*)(lds + 24576);

    const int t = threadIdx.x;
    const int b  = blockIdx.x >> 2;
    const int s0 = (blockIdx.x & 3) << 5;
    const int wid = t >> 6, lane = t & 63;
    const int l16 = lane & 15, quad = lane >> 4;

    const int se = t >> 3, e8 = t & 7;
    const int dw = t >> 1, half = t & 1;
    const float* egp = e + (size_t)(b * S_ + s0 + se) * E_ + e8 * 8;
    const float* wgp = W + (size_t)dw * E_ + half * 32;
    const int eoff = (se * 128 + e8 * 16) ^ ((se & 7) << 4);
    const int woffb = dw * 128 + half * 64;
    const int wswz = (dw & 7) << 4;

    float4 ve[2], vw[8];
#define K1_LOAD(KC)                                            \
    do {                                                       \
        ve[0] = *(const float4*)(egp + (KC));                  \
        ve[1] = *(const float4*)(egp + (KC) + 4);              \
        _Pragma("unroll")                                      \
        for (int x = 0; x < 8; ++x)                            \
            vw[x] = *(const float4*)(wgp + (KC) + x * 4);      \
    } while (0)

    K1_LOAD(0);

    f32x4 acc[2][2];
#pragma unroll
    for (int mt = 0; mt < 2; ++mt)
#pragma unroll
        for (int nt = 0; nt < 2; ++nt) acc[mt][nt] = (f32x4)0.f;

#pragma unroll 1
    for (int kc = 0; kc < 4; ++kc) {
        {
            f16x8 vh, vl;
#pragma unroll
            for (int x = 0; x < 8; ++x) {
                const float v = (x < 4) ? ((const float*)&ve[0])[x]
                                        : ((const float*)&ve[1])[x - 4];
                const f16 h_ = (f16)v;
                vh[x] = h_; vl[x] = (f16)(v - (float)h_);
            }
            *(f16x8*)((char*)ehB + eoff) = vh;
            *(f16x8*)((char*)elB + eoff) = vl;
        }
#pragma unroll
        for (int g = 0; g < 4; ++g) {
            f16x8 vh, vl;
#pragma unroll
            for (int x = 0; x < 8; ++x) {
                const float v = (x < 4) ? ((const float*)&vw[2 * g])[x]
                                        : ((const float*)&vw[2 * g + 1])[x - 4];
                const f16 h_ = (f16)v;
                vh[x] = h_; vl[x] = (f16)(v - (float)h_);
            }
            const int off = (woffb + g * 16) ^ wswz;
            *(f16x8*)((char*)WhB + off) = vh;
            *(f16x8*)((char*)WlB + off) = vl;
        }
        if (kc < 3) K1_LOAD((kc + 1) * 64);
        bar_lds();                                     // A: tiles ready

#pragma unroll
        for (int kke = 0; kke < 2; ++kke) {
            const int ebyte = kke * 64 + quad * 16;
            f16x8 ah[2], al[2], bh[2], bl[2];
#pragma unroll
            for (int mt = 0; mt < 2; ++mt) {
                const int row = mt * 16 + l16;
                const int off = (row * 128 + ebyte) ^ ((row & 7) << 4);
                ah[mt] = *(const f16x8*)((const char*)ehB + off);
                al[mt] = *(const f16x8*)((const char*)elB + off);
            }
#pragma unroll
            for (int nt = 0; nt < 2; ++nt) {
                const int dr = (wid << 5) + nt * 16 + l16;
                const int off = (dr * 128 + ebyte) ^ ((dr & 7) << 4);
                bh[nt] = *(const f16x8*)((const char*)WhB + off);
                bl[nt] = *(const f16x8*)((const char*)WlB + off);
            }
#pragma unroll
            for (int mt = 0; mt < 2; ++mt)
#pragma unroll
                for (int nt = 0; nt < 2; ++nt) {
                    acc[mt][nt] = mfma16(ah[mt], bh[nt], acc[mt][nt]);
                    acc[mt][nt] = mfma16(ah[mt], bl[nt], acc[mt][nt]);
                    acc[mt][nt] = mfma16(al[mt], bh[nt], acc[mt][nt]);
                }
        }
        bar_lds();                                     // B: safe to overwrite
    }
#undef K1_LOAD

    f16 hi[2][2][4], lo[2][2][4];
#pragma unroll
    for (int nt = 0; nt < 2; ++nt) {
        const int d = (wid << 5) + nt * 16 + l16;
        const float bz = bias[d];
#pragma unroll
        for (int mt = 0; mt < 2; ++mt)
#pragma unroll
            for (int r = 0; r < 4; ++r) {
                const float val = acc[mt][nt][r] + bz;
                const f16 h_ = (f16)val;
                hi[mt][nt][r] = h_;
                lo[mt][nt][r] = (f16)(val - (float)h_);
            }
    }

#pragma unroll
    for (int mt = 0; mt < 2; ++mt)
#pragma unroll
        for (int nt = 0; nt < 2; ++nt) {
            const int d = (wid << 5) + nt * 16 + l16;
            const int sg = s0 + mt * 16 + quad * 4;
            unsigned* p = epT_h + (size_t)(b * D_ + d) * 64 + (sg >> 1);
            p[0] = pack2(hi[mt][nt][0], hi[mt][nt][1]);
            p[1] = pack2(hi[mt][nt][2], hi[mt][nt][3]);
        }

    f16* oAh = (f16*)lds;                   // [32][136]
    f16* oAl = (f16*)(lds + 8704);
#pragma unroll
    for (int mt = 0; mt < 2; ++mt)
#pragma unroll
        for (int nt = 0; nt < 2; ++nt)
#pragma unroll
            for (int r = 0; r < 4; ++r) {
                const int sl = mt * 16 + quad * 4 + r;
                const int d = (wid << 5) + nt * 16 + l16;
                oAh[sl * 136 + d] = hi[mt][nt][r];
                oAl[sl * 136 + d] = lo[mt][nt][r];
            }
    bar_lds();
    {
        const int sl = t >> 3, j8 = (t & 7) * 8;
        const char* rh = (const char*)oAh + sl * 272 + j8 * 4;
        const char* rl = (const char*)oAl + sl * 272 + j8 * 4;
        uint4* dh = (uint4*)(epA_h + (size_t)(b * S_ + s0 + sl) * 64 + j8);
        uint4* dl = (uint4*)(epA_l + (size_t)(b * S_ + s0 + sl) * 64 + j8);
        dh[0] = *(const uint4*)rh; dh[1] = *(const uint4*)(rh + 16);
        dl[0] = *(const uint4*)rl; dl[1] = *(const uint4*)(rl + 16);
    }
}

// ---------------------------------------------------------------------------
// K2 v5 = v4 geometry (64-col tile, 4096 WGs, XCD swizzle) with LDS cut to
// 32768 B EXACTLY -> 5 WG/CU (was 3). Residency is the proven bottleneck:
// v4 showed ideal traffic (FETCH 69MB) at 10% MfmaUtil and time==v1; model
// time = chain_latency/residency fit all rounds.
//  - bT (16KB) + red (1KB) now ALIAS the dead hT buffer; requires one extra
//    LDS-only barrier (B) after phase 1 (hT last read) before red/bT writes.
//    Barriers: A (hT ready), B (hT dead), C (red ready), D (bT ready).
//  - kk=0 ep fragment loads of both phases hoisted so L2 latency hides under
//    staging-cvt (phase 1) and softmax (phase 2) instead of heading the
//    MFMA dependency chains.
//  - everything else byte-identical to v4.
// ---------------------------------------------------------------------------
__global__ __launch_bounds__(256, 5) void k2_attn(
    const float* __restrict__ h, const f16* __restrict__ epA_h,
    const f16* __restrict__ epA_l, const f16* __restrict__ epT_h,
    float* __restrict__ out)
{
    __shared__ __align__(16) unsigned char hTb[32768];   // hi|lo; then bT+red

    f16*   bTp  = (f16*)hTb;                 // [64 n][128 s] swz (aliases hT)
    float* redb = (float*)(hTb + 16384);     // [64 n][4 w]   (aliases hT lo)

    const int phys = blockIdx.x;
    const int L = (phys & 7) * 512 + (phys >> 3);        // XCD-contiguous
    const int b  = L >> 6;
    const int n0 = (L & 63) << 6;

    const int t = threadIdx.x;
    const int wid = t >> 6, lane = t & 63;
    const int l16 = lane & 15, quad = lane >> 4;
    const int sb = wid << 5, db = wid << 5;

    // ---- stage h[b][:, n0:n0+64]: thread = (col sn, rows wid*32..+31) ----
    const int sn = t & 63;
    float va[32];
    {
        const float* hp = h + (size_t)(b * D_ + wid * 32) * N_ + n0 + sn;
#pragma unroll
        for (int x = 0; x < 32; ++x) va[x] = hp[(size_t)x * N_];
    }

    // hoist phase-1 kk=0 A-fragment loads (latency hides under cvt+barA)
    const f16* Ah = epA_h + (size_t)(b * S_ + sb + l16) * D_ + quad * 8;
    const f16* Al = epA_l + (size_t)(b * S_ + sb + l16) * D_ + quad * 8;
    f16x8 ah0[2], al0[2];
    ah0[0] = *(const f16x8*)(Ah);
    al0[0] = *(const f16x8*)(Al);
    ah0[1] = *(const f16x8*)(Ah + 16 * D_);
    al0[1] = *(const f16x8*)(Al + 16 * D_);

    {
        const int swzn = (sn & 15) << 4;
#pragma unroll
        for (int g = 0; g < 4; ++g) {
            f16x8 vh, vl;
#pragma unroll
            for (int x = 0; x < 8; ++x) {
                const float v = va[g * 8 + x];
                const f16 h_ = (f16)v;
                vh[x] = h_; vl[x] = (f16)(v - (float)h_);
            }
            const int off = (sn * 256 + wid * 64 + g * 16) ^ swzn;
            *(f16x8*)(hTb + off) = vh;
            *(f16x8*)(hTb + 16384 + off) = vl;
        }
    }
    bar_lds();                                           // A: hT ready

    // ---- phase 1: sc[128 s][64 n] = ep x h (3 mfma chains) ----
    f32x4 acc[2][4];
#pragma unroll
    for (int mt = 0; mt < 2; ++mt)
#pragma unroll
        for (int nt = 0; nt < 4; ++nt) acc[mt][nt] = (f32x4)0.f;

#pragma unroll
    for (int kk = 0; kk < 4; ++kk) {
        const int dcb = kk * 64 + quad * 16;
        f16x8 bh[4], bl[4];
#pragma unroll
        for (int nt = 0; nt < 4; ++nt) {
            const int n = (nt << 4) + l16;
            const int off = (n * 256 + dcb) ^ ((n & 15) << 4);
            bh[nt] = *(const f16x8*)(hTb + off);
            bl[nt] = *(const f16x8*)(hTb + 16384 + off);
        }
#pragma unroll
        for (int mt = 0; mt < 2; ++mt) {
            const f16x8 ah = (kk == 0) ? ah0[mt]
                : *(const f16x8*)(Ah + mt * 16 * D_ + kk * 32);
            const f16x8 al = (kk == 0) ? al0[mt]
                : *(const f16x8*)(Al + mt * 16 * D_ + kk * 32);
#pragma unroll
            for (int nt = 0; nt < 4; ++nt) {
                acc[mt][nt] = mfma16(ah, bh[nt], acc[mt][nt]);
                acc[mt][nt] = mfma16(ah, bl[nt], acc[mt][nt]);
                acc[mt][nt] = mfma16(al, bh[nt], acc[mt][nt]);
            }
        }
    }

    // hoist phase-2 kk=0 A loads (hide under softmax + barriers B/C/D)
    const f16* At = epT_h + (size_t)(b * D_ + db + l16) * S_ + quad * 8;
    f16x8 av0[2];
    av0[0] = *(const f16x8*)(At);
    av0[1] = *(const f16x8*)(At + 16 * S_);

    // ---- softmax over s (constant shift, register-only until red write) ----
    float ps[4];
#pragma unroll
    for (int nt = 0; nt < 4; ++nt) {
        float p = 0.f;
#pragma unroll
        for (int mt = 0; mt < 2; ++mt)
#pragma unroll
            for (int r = 0; r < 4; ++r) {
                const float e_ = __expf(acc[mt][nt][r] - 30.f);
                acc[mt][nt][r] = e_;
                p += e_;
            }
        p += __shfl_xor(p, 16);
        p += __shfl_xor(p, 32);
        ps[nt] = p;
    }
    bar_lds();                                           // B: hT dead
#pragma unroll
    for (int nt = 0; nt < 4; ++nt)
        if (quad == 0) redb[(((nt << 4) + l16) << 2) + wid] = ps[nt];
    bar_lds();                                           // C: sums ready

#pragma unroll
    for (int nt = 0; nt < 4; ++nt) {
        const int n = (nt << 4) + l16;
        const f32x4 s4 = *(const f32x4*)(redb + (n << 2));
        const float inv = 1.f / (s4[0] + s4[1] + s4[2] + s4[3]);
#pragma unroll
        for (int mt = 0; mt < 2; ++mt) {
            uint2 pk;
            pk.x = pack2((f16)(acc[mt][nt][0] * inv),
                         (f16)(acc[mt][nt][1] * inv));
            pk.y = pack2((f16)(acc[mt][nt][2] * inv),
                         (f16)(acc[mt][nt][3] * inv));
            const int bo = (n * 256 + wid * 64 + mt * 32 + quad * 8)
                           ^ ((n & 15) << 4);
            *(uint2*)((char*)bTp + bo) = pk;
        }
    }
    bar_lds();                                           // D: beta ready

    // ---- phase 2: c[128 d][64 n] = epT x beta ----
    f32x4 a2[2][4];
#pragma unroll
    for (int mt = 0; mt < 2; ++mt)
#pragma unroll
        for (int nt = 0; nt < 4; ++nt) a2[mt][nt] = (f32x4)0.f;

#pragma unroll
    for (int kk = 0; kk < 4; ++kk) {
        const int scb = kk * 64 + quad * 16;
        f16x8 bb[4];
#pragma unroll
        for (int nt = 0; nt < 4; ++nt) {
            const int n = (nt << 4) + l16;
            const int off = (n * 256 + scb) ^ ((n & 15) << 4);
            bb[nt] = *(const f16x8*)((const char*)bTp + off);
        }
#pragma unroll
        for (int mt = 0; mt < 2; ++mt) {
            const f16x8 av = (kk == 0) ? av0[mt]
                : *(const f16x8*)(At + mt * 16 * S_ + kk * 32);
#pragma unroll
            for (int nt = 0; nt < 4; ++nt)
                a2[mt][nt] = mfma16(av, bb[nt], a2[mt][nt]);
        }
    }

    // ---- direct global store ----
    float* ob = out + (size_t)(b * D_ + db) * N_ + n0;
#pragma unroll
    for (int mt = 0; mt < 2; ++mt)
#pragma unroll
        for (int nt = 0; nt < 4; ++nt)
#pragma unroll
            for (int r = 0; r < 4; ++r)
                ob[(size_t)(mt * 16 + quad * 4 + r) * N_ + (nt << 4) + l16] =
                    a2[mt][nt][r];
}

extern "C" void kernel_launch(void* const* d_in, const int* in_sizes, int n_in,
                              void* d_out, int out_size, void* d_ws, size_t ws_size,
                              hipStream_t stream) {
    const float* e    = (const float*)d_in[0];
    const float* h    = (const float*)d_in[1];
    const float* W    = (const float*)d_in[2];
    const float* bias = (const float*)d_in[3];
    float* out = (float*)d_out;

    unsigned* epA_h = (unsigned*)d_ws;                  // 2 MB
    unsigned* epA_l = epA_h + (B_ * S_ * D_ / 2);       // 2 MB
    unsigned* epT_h = epA_l + (B_ * S_ * D_ / 2);       // 2 MB

    hipLaunchKernelGGL(k1_ep, dim3(B_ * 4), dim3(256), 0, stream,
                       e, W, bias, epA_h, epA_l, epT_h);
    hipLaunchKernelGGL(k2_attn, dim3(B_ * 64), dim3(256), 0, stream,
                       h, (const f16*)epA_h, (const f16*)epA_l,
                       (const f16*)epT_h, out);
}

// Round 6
// 299.920 us; speedup vs baseline: 1.0827x; 1.0827x over previous
//
#include <hip/hip_runtime.h>
#include <math.h>

#define B_ 64
#define S_ 128
#define E_ 256
#define D_ 128
#define N_ 4096

typedef _Float16 f16;
typedef _Float16 f16x8 __attribute__((ext_vector_type(8)));
typedef float f32x4 __attribute__((ext_vector_type(4)));

__device__ __forceinline__ unsigned pack2(f16 a, f16 b) {
    union { f16 h[2]; unsigned u; } x;
    x.h[0] = a; x.h[1] = b; return x.u;
}

__device__ __forceinline__ f32x4 mfma16(f16x8 a, f16x8 b, f32x4 c) {
    return __builtin_amdgcn_mfma_f32_16x16x32_f16(a, b, c, 0, 0, 0);
}

// LDS-only barrier: does NOT drain vmcnt, so in-flight global loads survive.
__device__ __forceinline__ void bar_lds() {
    asm volatile("s_waitcnt lgkmcnt(0)" ::: "memory");
    __builtin_amdgcn_s_barrier();
    asm volatile("" ::: "memory");
}

// ---------------------------------------------------------------------------
// K1: unchanged from round 4 (MFMA 3-chain; residual is invariant under k1
// implementation, so k1 stays frozen).
// ---------------------------------------------------------------------------
__global__ __launch_bounds__(256) void k1_ep(
    const float* __restrict__ e, const float* __restrict__ W,
    const float* __restrict__ bias,
    unsigned* __restrict__ epA_h, unsigned* __restrict__ epA_l,
    unsigned* __restrict__ epT_h)
{
    __shared__ __align__(16) unsigned char lds[40960];
    f16* ehB = (f16*)lds;                    // [32][64] rows 128B, swz
    f16* elB = (f16*)(lds + 4096);
    f16* WhB = (f16*)(lds + 8192);           // [128][64] rows 128B, swz
    f16* WlB = (f16*)(lds + 24576);

    const int t = threadIdx.x;
    const int b  = blockIdx.x >> 2;
    const int s0 = (blockIdx.x & 3) << 5;
    const int wid = t >> 6, lane = t & 63;
    const int l16 = lane & 15, quad = lane >> 4;

    const int se = t >> 3, e8 = t & 7;
    const int dw = t >> 1, half = t & 1;
    const float* egp = e + (size_t)(b * S_ + s0 + se) * E_ + e8 * 8;
    const float* wgp = W + (size_t)dw * E_ + half * 32;
    const int eoff = (se * 128 + e8 * 16) ^ ((se & 7) << 4);
    const int woffb = dw * 128 + half * 64;
    const int wswz = (dw & 7) << 4;

    float4 ve[2], vw[8];
#define K1_LOAD(KC)                                            \
    do {                                                       \
        ve[0] = *(const float4*)(egp + (KC));                  \
        ve[1] = *(const float4*)(egp + (KC) + 4);              \
        _Pragma("unroll")                                      \
        for (int x = 0; x < 8; ++x)                            \
            vw[x] = *(const float4*)(wgp + (KC) + x * 4);      \
    } while (0)

    K1_LOAD(0);

    f32x4 acc[2][2];
#pragma unroll
    for (int mt = 0; mt < 2; ++mt)
#pragma unroll
        for (int nt = 0; nt < 2; ++nt) acc[mt][nt] = (f32x4)0.f;

#pragma unroll 1
    for (int kc = 0; kc < 4; ++kc) {
        {
            f16x8 vh, vl;
#pragma unroll
            for (int x = 0; x < 8; ++x) {
                const float v = (x < 4) ? ((const float*)&ve[0])[x]
                                        : ((const float*)&ve[1])[x - 4];
                const f16 h_ = (f16)v;
                vh[x] = h_; vl[x] = (f16)(v - (float)h_);
            }
            *(f16x8*)((char*)ehB + eoff) = vh;
            *(f16x8*)((char*)elB + eoff) = vl;
        }
#pragma unroll
        for (int g = 0; g < 4; ++g) {
            f16x8 vh, vl;
#pragma unroll
            for (int x = 0; x < 8; ++x) {
                const float v = (x < 4) ? ((const float*)&vw[2 * g])[x]
                                        : ((const float*)&vw[2 * g + 1])[x - 4];
                const f16 h_ = (f16)v;
                vh[x] = h_; vl[x] = (f16)(v - (float)h_);
            }
            const int off = (woffb + g * 16) ^ wswz;
            *(f16x8*)((char*)WhB + off) = vh;
            *(f16x8*)((char*)WlB + off) = vl;
        }
        if (kc < 3) K1_LOAD((kc + 1) * 64);
        bar_lds();                                     // A: tiles ready

#pragma unroll
        for (int kke = 0; kke < 2; ++kke) {
            const int ebyte = kke * 64 + quad * 16;
            f16x8 ah[2], al[2], bh[2], bl[2];
#pragma unroll
            for (int mt = 0; mt < 2; ++mt) {
                const int row = mt * 16 + l16;
                const int off = (row * 128 + ebyte) ^ ((row & 7) << 4);
                ah[mt] = *(const f16x8*)((const char*)ehB + off);
                al[mt] = *(const f16x8*)((const char*)elB + off);
            }
#pragma unroll
            for (int nt = 0; nt < 2; ++nt) {
                const int dr = (wid << 5) + nt * 16 + l16;
                const int off = (dr * 128 + ebyte) ^ ((dr & 7) << 4);
                bh[nt] = *(const f16x8*)((const char*)WhB + off);
                bl[nt] = *(const f16x8*)((const char*)WlB + off);
            }
#pragma unroll
            for (int mt = 0; mt < 2; ++mt)
#pragma unroll
                for (int nt = 0; nt < 2; ++nt) {
                    acc[mt][nt] = mfma16(ah[mt], bh[nt], acc[mt][nt]);
                    acc[mt][nt] = mfma16(ah[mt], bl[nt], acc[mt][nt]);
                    acc[mt][nt] = mfma16(al[mt], bh[nt], acc[mt][nt]);
                }
        }
        bar_lds();                                     // B: safe to overwrite
    }
#undef K1_LOAD

    f16 hi[2][2][4], lo[2][2][4];
#pragma unroll
    for (int nt = 0; nt < 2; ++nt) {
        const int d = (wid << 5) + nt * 16 + l16;
        const float bz = bias[d];
#pragma unroll
        for (int mt = 0; mt < 2; ++mt)
#pragma unroll
            for (int r = 0; r < 4; ++r) {
                const float val = acc[mt][nt][r] + bz;
                const f16 h_ = (f16)val;
                hi[mt][nt][r] = h_;
                lo[mt][nt][r] = (f16)(val - (float)h_);
            }
    }

#pragma unroll
    for (int mt = 0; mt < 2; ++mt)
#pragma unroll
        for (int nt = 0; nt < 2; ++nt) {
            const int d = (wid << 5) + nt * 16 + l16;
            const int sg = s0 + mt * 16 + quad * 4;
            unsigned* p = epT_h + (size_t)(b * D_ + d) * 64 + (sg >> 1);
            p[0] = pack2(hi[mt][nt][0], hi[mt][nt][1]);
            p[1] = pack2(hi[mt][nt][2], hi[mt][nt][3]);
        }

    f16* oAh = (f16*)lds;                   // [32][136]
    f16* oAl = (f16*)(lds + 8704);
#pragma unroll
    for (int mt = 0; mt < 2; ++mt)
#pragma unroll
        for (int nt = 0; nt < 2; ++nt)
#pragma unroll
            for (int r = 0; r < 4; ++r) {
                const int sl = mt * 16 + quad * 4 + r;
                const int d = (wid << 5) + nt * 16 + l16;
                oAh[sl * 136 + d] = hi[mt][nt][r];
                oAl[sl * 136 + d] = lo[mt][nt][r];
            }
    bar_lds();
    {
        const int sl = t >> 3, j8 = (t & 7) * 8;
        const char* rh = (const char*)oAh + sl * 272 + j8 * 4;
        const char* rl = (const char*)oAl + sl * 272 + j8 * 4;
        uint4* dh = (uint4*)(epA_h + (size_t)(b * S_ + s0 + sl) * 64 + j8);
        uint4* dl = (uint4*)(epA_l + (size_t)(b * S_ + s0 + sl) * 64 + j8);
        dh[0] = *(const uint4*)rh; dh[1] = *(const uint4*)(rh + 16);
        dl[0] = *(const uint4*)rl; dl[1] = *(const uint4*)(rl + 16);
    }
}

// ---------------------------------------------------------------------------
// K2 v6 = v4's exact body (launch_bounds(256,3) -> the proven 68-VGPR
// no-spill allocation; NO hoisted fragment loads) with ONE change:
// bT (16KB) + red (1KB) alias into the dead hT buffer -> LDS 50176 -> 32768 B
// = exactly 5 WG/CU (5 x 32768 = 163840 = full pool). v4 proved VGPR=68
// supports 7 waves/SIMD, so LDS was the only residency blocker.
// Cost: one extra LDS-only barrier (B) between phase 1's last hT read and
// the red write. Barriers: A (hT ready), B (hT dead), C (red), D (bT).
// v5's regression was a spill artifact (VGPR 48, +115MB scratch traffic
// from launch_bounds(256,5)) - not a test of residency.
// ---------------------------------------------------------------------------
__global__ __launch_bounds__(256, 3) void k2_attn(
    const float* __restrict__ h, const f16* __restrict__ epA_h,
    const f16* __restrict__ epA_l, const f16* __restrict__ epT_h,
    float* __restrict__ out)
{
    __shared__ __align__(16) unsigned char hTb[32768];   // hi|lo; then bT+red

    f16*   bTp  = (f16*)hTb;                 // [64 n][128 s] swz (aliases hT hi)
    float* redb = (float*)(hTb + 16384);     // [64 n][4 w]   (aliases hT lo)

    const int phys = blockIdx.x;
    const int L = (phys & 7) * 512 + (phys >> 3);        // XCD-contiguous
    const int b  = L >> 6;
    const int n0 = (L & 63) << 6;

    const int t = threadIdx.x;
    const int wid = t >> 6, lane = t & 63;
    const int l16 = lane & 15, quad = lane >> 4;

    // ---- stage h[b][:, n0:n0+64]: thread = (col sn, rows wid*32..+31) ----
    const int sn = t & 63;
    float va[32];
    {
        const float* hp = h + (size_t)(b * D_ + wid * 32) * N_ + n0 + sn;
#pragma unroll
        for (int x = 0; x < 32; ++x) va[x] = hp[(size_t)x * N_];
    }
    {
        const int swzn = (sn & 15) << 4;
#pragma unroll
        for (int g = 0; g < 4; ++g) {
            f16x8 vh, vl;
#pragma unroll
            for (int x = 0; x < 8; ++x) {
                const float v = va[g * 8 + x];
                const f16 h_ = (f16)v;
                vh[x] = h_; vl[x] = (f16)(v - (float)h_);
            }
            const int off = (sn * 256 + wid * 64 + g * 16) ^ swzn;
            *(f16x8*)(hTb + off) = vh;
            *(f16x8*)(hTb + 16384 + off) = vl;
        }
    }
    bar_lds();                                           // A: hT ready

    // ---- phase 1: sc[128 s][64 n] = ep x h (3 mfma chains) ----
    const int sb = wid << 5;
    f32x4 acc[2][4];
#pragma unroll
    for (int mt = 0; mt < 2; ++mt)
#pragma unroll
        for (int nt = 0; nt < 4; ++nt) acc[mt][nt] = (f32x4)0.f;

    const f16* Ah = epA_h + (size_t)(b * S_ + sb + l16) * D_ + quad * 8;
    const f16* Al = epA_l + (size_t)(b * S_ + sb + l16) * D_ + quad * 8;
#pragma unroll
    for (int kk = 0; kk < 4; ++kk) {
        const int dcb = kk * 64 + quad * 16;             // byte off in row
        f16x8 bh[4], bl[4];
#pragma unroll
        for (int nt = 0; nt < 4; ++nt) {
            const int n = (nt << 4) + l16;
            const int off = (n * 256 + dcb) ^ ((n & 15) << 4);
            bh[nt] = *(const f16x8*)(hTb + off);
            bl[nt] = *(const f16x8*)(hTb + 16384 + off);
        }
#pragma unroll
        for (int mt = 0; mt < 2; ++mt) {
            const f16x8 ah = *(const f16x8*)(Ah + mt * 16 * D_ + kk * 32);
            const f16x8 al = *(const f16x8*)(Al + mt * 16 * D_ + kk * 32);
#pragma unroll
            for (int nt = 0; nt < 4; ++nt) {
                acc[mt][nt] = mfma16(ah, bh[nt], acc[mt][nt]);
                acc[mt][nt] = mfma16(ah, bl[nt], acc[mt][nt]);
                acc[mt][nt] = mfma16(al, bh[nt], acc[mt][nt]);
            }
        }
    }

    // ---- softmax over s (constant shift; regs only until red write) ----
    float ps[4];
#pragma unroll
    for (int nt = 0; nt < 4; ++nt) {
        float p = 0.f;
#pragma unroll
        for (int mt = 0; mt < 2; ++mt)
#pragma unroll
            for (int r = 0; r < 4; ++r) {
                const float e_ = __expf(acc[mt][nt][r] - 30.f);
                acc[mt][nt][r] = e_;
                p += e_;
            }
        p += __shfl_xor(p, 16);
        p += __shfl_xor(p, 32);
        ps[nt] = p;
    }
    bar_lds();                                           // B: hT dead
#pragma unroll
    for (int nt = 0; nt < 4; ++nt)
        if (quad == 0) redb[(((nt << 4) + l16) << 2) + wid] = ps[nt];
    bar_lds();                                           // C: sums ready

#pragma unroll
    for (int nt = 0; nt < 4; ++nt) {
        const int n = (nt << 4) + l16;
        const f32x4 s4 = *(const f32x4*)(redb + (n << 2));
        const float inv = 1.f / (s4[0] + s4[1] + s4[2] + s4[3]);
#pragma unroll
        for (int mt = 0; mt < 2; ++mt) {
            uint2 pk;
            pk.x = pack2((f16)(acc[mt][nt][0] * inv),
                         (f16)(acc[mt][nt][1] * inv));
            pk.y = pack2((f16)(acc[mt][nt][2] * inv),
                         (f16)(acc[mt][nt][3] * inv));
            const int bo = (n * 256 + wid * 64 + mt * 32 + quad * 8)
                           ^ ((n & 15) << 4);
            *(uint2*)((char*)bTp + bo) = pk;
        }
    }
    bar_lds();                                           // D: beta ready

    // ---- phase 2: c[128 d][64 n] = epT x beta ----
    const int db = wid << 5;
    f32x4 a2[2][4];
#pragma unroll
    for (int mt = 0; mt < 2; ++mt)
#pragma unroll
        for (int nt = 0; nt < 4; ++nt) a2[mt][nt] = (f32x4)0.f;

    const f16* At = epT_h + (size_t)(b * D_ + db + l16) * S_ + quad * 8;
#pragma unroll
    for (int kk = 0; kk < 4; ++kk) {
        const int scb = kk * 64 + quad * 16;
        f16x8 bb[4];
#pragma unroll
        for (int nt = 0; nt < 4; ++nt) {
            const int n = (nt << 4) + l16;
            const int off = (n * 256 + scb) ^ ((n & 15) << 4);
            bb[nt] = *(const f16x8*)((const char*)bTp + off);
        }
#pragma unroll
        for (int mt = 0; mt < 2; ++mt) {
            const f16x8 av = *(const f16x8*)(At + mt * 16 * S_ + kk * 32);
#pragma unroll
            for (int nt = 0; nt < 4; ++nt)
                a2[mt][nt] = mfma16(av, bb[nt], a2[mt][nt]);
        }
    }

    // ---- direct global store ----
    float* ob = out + (size_t)(b * D_ + db) * N_ + n0;
#pragma unroll
    for (int mt = 0; mt < 2; ++mt)
#pragma unroll
        for (int nt = 0; nt < 4; ++nt)
#pragma unroll
            for (int r = 0; r < 4; ++r)
                ob[(size_t)(mt * 16 + quad * 4 + r) * N_ + (nt << 4) + l16] =
                    a2[mt][nt][r];
}

extern "C" void kernel_launch(void* const* d_in, const int* in_sizes, int n_in,
                              void* d_out, int out_size, void* d_ws, size_t ws_size,
                              hipStream_t stream) {
    const float* e    = (const float*)d_in[0];
    const float* h    = (const float*)d_in[1];
    const float* W    = (const float*)d_in[2];
    const float* bias = (const float*)d_in[3];
    float* out = (float*)d_out;

    unsigned* epA_h = (unsigned*)d_ws;                  // 2 MB
    unsigned* epA_l = epA_h + (B_ * S_ * D_ / 2);       // 2 MB
    unsigned* epT_h = epA_l + (B_ * S_ * D_ / 2);       // 2 MB

    hipLaunchKernelGGL(k1_ep, dim3(B_ * 4), dim3(256), 0, stream,
                       e, W, bias, epA_h, epA_l, epT_h);
    hipLaunchKernelGGL(k2_attn, dim3(B_ * 64), dim3(256), 0, stream,
                       h, (const f16*)epA_h, (const f16*)epA_l,
                       (const f16*)epT_h, out);
}